// Round 12
// baseline (248.553 us; speedup 1.0000x reference)
//
#include <hip/hip_runtime.h>
#include <hip/hip_bf16.h>

// Problem constants
#define NB   8      // batch
#define NM   288    // Bkk = 32*3*3
#define NN   1152   // Cww = 32*6*6
#define NUV  36     // w*w
#define ND   16

// ws layout (float offsets; P/Wt regions hold bf16 in half the space)
#define OFF_P    0
#define SZ_P     (NB*NUV*NM*ND)      // patches, bf16 [b][uv][m][k*4+j]
#define OFF_WT   (OFF_P + SZ_P)
#define SZ_WT    (32*NM*ND)          // W transposed, bf16 [z][m][i*4+j]
#define OFF_ACT  (OFF_WT + SZ_WT)
#define SZ_ACT   (NB*NUV*NM)         // act, f32 [b][uv][m]
#define OFF_PA   (OFF_ACT + SZ_ACT)
#define SZ_PA    (NB*NN*NM)          // ap = act*sum_d exp(log_p), f32 [b][n][m]
#define OFF_RS   (OFF_PA + SZ_PA)
#define SZ_RS    (NB*NM)             // 1 / sum_n ap, [b][m]
#define OFF_FLAG (OFF_RS + SZ_RS)    // dtype flag

#define HALF_LOG_2PI 0.9189385332046727f
#define NEG_BIG      (-1.0e30f)

__device__ __forceinline__ float ldin(const void* p, int i, int f32) {
    return f32 ? ((const float*)p)[i]
               : __bfloat162float(((const __hip_bfloat16*)p)[i]);
}

__device__ __forceinline__ unsigned short bfbits(float f) {
    __hip_bfloat16 h = __float2bfloat16(f);
    return __builtin_bit_cast(unsigned short, h);
}

// packed bf16x2 dot with f32 accumulate: d = a.lo*b.lo + a.hi*b.hi + c
__device__ __forceinline__ float dot2bf(unsigned a, unsigned b, float c) {
    float d;
    asm("v_dot2_f32_bf16 %0, %1, %2, %3" : "=v"(d) : "v"(a), "v"(b), "v"(c));
    return d;
}

// inline dtype sniff (r3-r11 verified: flag==0 on this harness)
__device__ __forceinline__ int sniff(const unsigned short* u16) {
    int wild = 0;
    for (int i = 0; i < 64; ++i) {
        int ex = (u16[i] >> 7) & 0xFF;
        if (ex >= 133) ++wild;
    }
    return (wild >= 4) ? 1 : 0;
}

// (b,s)-tiled prep: stage poses[b,:,s,:,:] + acts[b,s,:,:] in LDS, emit bf16 P
// (uint4 stores) and f32 act. Blocks 256..291 transpose W (uint4 stores).
// dtype flag computed per-block inline (no separate detect launch); block 0
// publishes it to ws for em_iter's epilogue.
__global__ __launch_bounds__(256) void prep_kernel(
    const void* __restrict__ poses, const void* __restrict__ acts,
    const void* __restrict__ Wb, __hip_bfloat16* __restrict__ P,
    __hip_bfloat16* __restrict__ Wt, float* __restrict__ A36,
    int* __restrict__ flagw)
{
    const int blk = blockIdx.x;
    const int tid = threadIdx.x;
    __shared__ int lflag;
    if (tid == 0) {
        int f = sniff((const unsigned short*)poses);
        lflag = f;
        if (blk == 0) *flagw = f;
    }
    __syncthreads();
    const int f32 = lflag;

    if (blk < 256) {
        __shared__ float ps[16 * 196];
        __shared__ float asld[196];
        const int b = blk >> 5, s = blk & 31;
        for (int e = tid; e < 16 * 196; e += 256) {
            int c = e / 196, hw = e % 196;
            ps[e] = ldin(poses, ((b * 16 + c) * 32 + s) * 196 + hw, f32);
        }
        for (int e = tid; e < 196; e += 256)
            asld[e] = ldin(acts, (b * 32 + s) * 196 + e, f32);
        __syncthreads();
        // P emit: 324 rows x 2 halves; one uint4 (8 bf16) per work item
        for (int o2 = tid; o2 < 648; o2 += 256) {
            int row = o2 >> 1, half = o2 & 1;
            int uv = row / 9, xy = row % 9;
            int u = uv / 6, vv2 = uv % 6;
            int x = xy / 3, y = xy % 3;
            unsigned pk[4];
#pragma unroll
            for (int h = 0; h < 4; ++h) {
                unsigned lohi[2];
#pragma unroll
                for (int e = 0; e < 2; ++e) {
                    int kj = half * 8 + h * 2 + e;
                    int k = kj >> 2, j = kj & 3;
                    int idx = u * 96 + vv2 * 16 + j * 4 + k;   // torch view scramble
                    int c = idx / 36, rem = idx % 36;
                    int wi = rem / 6, wj = rem % 6;
                    lohi[e] = bfbits(ps[c * 196 + (2 * wi + x) * 14 + (2 * wj + y)]);
                }
                pk[h] = lohi[0] | (lohi[1] << 16);
            }
            *((uint4*)(P + (((size_t)((b * 36 + uv) * 288 + s * 9 + xy)) << 4) + half * 8)) =
                make_uint4(pk[0], pk[1], pk[2], pk[3]);
        }
        for (int o = tid; o < 324; o += 256) {
            int uv = o / 9, xy = o % 9;
            int u = uv / 6, vv2 = uv % 6;
            int x = xy / 3, y = xy % 3;
            A36[(b * 36 + uv) * 288 + s * 9 + xy] =
                asld[(2 * u + x) * 14 + (2 * vv2 + y)];
        }
    } else {
        int idx = (blk - 256) * 256 + tid;    // 0..9215 (z,m) pairs
        int z = idx / 288, m = idx % 288;
        unsigned pk[8];
#pragma unroll
        for (int h = 0; h < 8; ++h) {
            unsigned lo = bfbits(ldin(Wb, m * 512 + z * 16 + 2 * h, f32));
            unsigned hi = bfbits(ldin(Wb, m * 512 + z * 16 + 2 * h + 1, f32));
            pk[h] = lo | (hi << 16);
        }
        uint4* dst = (uint4*)(Wt + idx * 16);
        dst[0] = make_uint4(pk[0], pk[1], pk[2], pk[3]);
        dst[1] = make_uint4(pk[4], pk[5], pk[6], pk[7]);
    }
}

// One block per (b,n) — r7/r9 shape, LINEAR-domain routing weights (r12):
// Ra = act * ap * (1/sum_n ap) — no exp/log/max machinery in the t-stage;
// scale cancels in the division by sumW (guarded >= 1e-37). ell stage emits
// ap = clamp(act * sum_d exp(log_p), 1e-30) directly (no per-d max, no log).
// XCD swizzle: blockIdx = (g>>3)*256 + z*8 + (g&7), g = b*36+uv.
__global__ __launch_bounds__(288, 4) void em_iter(
    const unsigned short* __restrict__ wsP, const unsigned short* __restrict__ wsWt,
    const float* __restrict__ wsA, float* __restrict__ wsPA,
    const float* __restrict__ wsRS,
    const void* __restrict__ beta_v,
    const void* __restrict__ beta_a,
    const void* __restrict__ lambda_,
    void* __restrict__ outv, const int* __restrict__ flagp, int iter)
{
    __shared__ float red[NM * 17];   // [m][col]: 0..15 = v[d], 16 = Ra  (19.6 KB)
    __shared__ float paru[NM];       // [d][c] partial sum(w*v)
    __shared__ float parv[NM];       // [d][c] partial sum(w*v*v)
    __shared__ float paruW[18];      // [c] partial sum(w)
    __shared__ float mul[16], nhil[16], ltl[16], ssl[16];

    const int tid = threadIdx.x;          // == m
    const int B   = blockIdx.x;
    const int rr  = B & 255;
    const int z   = rr >> 3;
    const int g   = ((B >> 8) << 3) | (rr & 7);   // b*36+uv
    const int b   = g / NUV;
    const int uv  = g % NUV;
    const int n   = z * NUV + uv;
    const int bn  = b * NN + n;

    // all global loads issued up front (bf16 W/P rows stay packed)
    const uint4* Wq = (const uint4*)(wsWt + ((z * NM + tid) << 4));
    const uint4* Pq = (const uint4*)(wsP + ((g * NM + tid) << 4));
    uint4 wq0 = Wq[0], wq1 = Wq[1];
    uint4 pq0 = Pq[0], pq1 = Pq[1];
    const float act = wsA[g * NM + tid];

    // routing weight, linear domain (scale-free)
    float Ra;
    if (iter == 0) Ra = act;   // R = 1/NN uniform; constant cancels
    else Ra = act * wsPA[(size_t)bn * NM + tid] * wsRS[b * NM + tid];

    // votes v[i*4+k] = sum_j W[i][j] P[k-major][j] via packed bf16 dot2
    unsigned Wa[4]  = {wq0.x, wq0.z, wq1.x, wq1.z};   // (j0,j1) of i
    unsigned Wb_[4] = {wq0.y, wq0.w, wq1.y, wq1.w};   // (j2,j3) of i
    unsigned Pa[4]  = {pq0.x, pq0.z, pq1.x, pq1.z};   // (j0,j1) of k
    unsigned Pb[4]  = {pq0.y, pq0.w, pq1.y, pq1.w};   // (j2,j3) of k
    float v[16];
#pragma unroll
    for (int i = 0; i < 4; ++i)
#pragma unroll
        for (int k = 0; k < 4; ++k)
            v[i * 4 + k] = dot2bf(Wa[i], Pa[k], dot2bf(Wb_[i], Pb[k], 0.f));

    // transpose: m-major stride 17 (odd -> bank-bijective, 2-way = free)
#pragma unroll
    for (int dd = 0; dd < 16; ++dd) red[tid * 17 + dd] = v[dd];
    red[tid * 17 + 16] = Ra;
    __syncthreads();                                        // B1

    // column sums: thread (d = tid&15, c = tid>>4) sums m = 16c..16c+15
    {
        const int d = tid & 15, c = tid >> 4;
        const float* base = &red[(c << 4) * 17];
        float s1 = 0.f, s2 = 0.f, sw = 0.f;
#pragma unroll
        for (int q = 0; q < 16; ++q) {
            float ww = base[q * 17 + 16];
            float vv = base[q * 17 + d];
            float t1 = ww * vv;
            s1 += t1; s2 += t1 * vv; sw += ww;
        }
        paru[d * 18 + c] = s1;
        parv[d * 18 + c] = s2;
        if (d == 0) paruW[c] = sw;
    }
    __syncthreads();                                        // B2

    float sW_f = 0.f;   // tid==0 copy survives into the iter3 epilogue
    if (tid < 16) {
        float sW = 0.f, S1 = 0.f, S2 = 0.f;
#pragma unroll
        for (int c = 0; c < 18; ++c) {
            sW += paruW[c];
            S1 += paru[tid * 18 + c];
            S2 += parv[tid * 18 + c];
        }
        sW = fmaxf(sW, 1e-37f);     // guard vs all-zero column (no 0/0)
        float mu = S1 / sW;
        float q2 = S2 / sW;
        float ss = fmaxf(q2 - mu * mu, 1e-30f);   // E[v^2]-mu^2 (r4-r11 verified)
        mul[tid]  = mu;
        ssl[tid]  = ss;
        nhil[tid] = -0.5f / ss;
        ltl[tid]  = fmaf(-0.5f, __logf(ss), -HALF_LOG_2PI);
        sW_f = sW;
    }
    __syncthreads();                                        // B3

    if (iter < 3) {
        // ap[m] = act * sum_d exp(log_p) — no per-d max (clamped; benign range
        // identical), no log. Exps issue as soon as each lp is ready.
        float s = 0.f;
#pragma unroll
        for (int dd = 0; dd < 16; ++dd) {
            float df = v[dd] - mul[dd];
            s += __expf(fmaf(df * df, nhil[dd], ltl[dd]));
        }
        wsPA[(size_t)bn * NM + tid] = fmaxf(act * s, 1e-30f);
    } else {
        const int f32 = *flagp;
        if (tid < 16) {
            if (f32) ((float*)outv)[(bn << 4) + tid] = mul[tid];
            else ((__hip_bfloat16*)outv)[(bn << 4) + tid] = __float2bfloat16(mul[tid]);
        }
        if (tid == 0) {
            float sumR = sW_f;   // linear domain: sum_m R*act directly
            float bv = ldin(beta_v, n, f32);
            float c = 0.f;
#pragma unroll
            for (int dd = 0; dd < 16; ++dd) c += bv + __logf(ssl[dd]);
            c *= sumR;
            float lam = ldin(lambda_, 0, f32);
            float ba  = ldin(beta_a, n, f32);
            float ao  = 1.f / (1.f + __expf(-(lam * (ba - c))));
            int oi = NB * NN * ND + bn;
            if (f32) ((float*)outv)[oi] = ao;
            else ((__hip_bfloat16*)outv)[oi] = __float2bfloat16(ao);
        }
    }
}

// Row-sum over n of ap[b][n][m] + reciprocal — single kernel, single pass
// (linear domain needs no max/exp/log). Block = (b, mt16): tid = n16*16+m16;
// 16 consecutive m per load group (64 B, coalesced). Deterministic order.
__global__ __launch_bounds__(256) void sum_kernel(const float* __restrict__ PA,
                                                  float* __restrict__ RS)
{
    __shared__ float red[16][17];
    const int blk = blockIdx.x;           // b*18 + mt
    const int b  = blk / 18, mt = blk % 18;
    const int n16 = threadIdx.x >> 4, m16 = threadIdx.x & 15;
    const int m = mt * 16 + m16;
    const float* base = PA + (size_t)b * NN * NM + m;
    float s = 0.f;
#pragma unroll
    for (int i = 0; i < 72; ++i) s += base[(size_t)(n16 + 16 * i) * NM];
    red[n16][m16] = s;
    __syncthreads();
    if (threadIdx.x < 16) {
        float t = 0.f;
#pragma unroll
        for (int q = 0; q < 16; ++q) t += red[q][threadIdx.x];
        RS[b * NM + mt * 16 + threadIdx.x] = 1.0f / t;   // t >= 288e-30 > 0
    }
}

extern "C" void kernel_launch(void* const* d_in, const int* in_sizes, int n_in,
                              void* d_out, int out_size, void* d_ws, size_t ws_size,
                              hipStream_t stream)
{
    const void* poses = d_in[0];
    const void* acts  = d_in[1];
    const void* lam   = d_in[2];
    const void* Wb    = d_in[3];
    const void* bv    = d_in[4];
    const void* ba    = d_in[5];

    float* ws  = (float*)d_ws;
    __hip_bfloat16* P  = (__hip_bfloat16*)(ws + OFF_P);
    __hip_bfloat16* Wt = (__hip_bfloat16*)(ws + OFF_WT);
    float* A36 = ws + OFF_ACT;
    float* PA  = ws + OFF_PA;
    float* RS  = ws + OFF_RS;
    int*  flag = (int*)(ws + OFF_FLAG);

    prep_kernel<<<292, 256, 0, stream>>>(poses, acts, Wb, P, Wt, A36, flag);

    for (int it = 0; it < 4; ++it) {
        em_iter<<<NB * NN, 288, 0, stream>>>((const unsigned short*)P,
                                             (const unsigned short*)Wt,
                                             A36, PA, RS, bv, ba, lam,
                                             d_out, flag, it);
        if (it < 3) {
            sum_kernel<<<NB * 18, 256, 0, stream>>>(PA, RS);
        }
    }
}